// Round 1
// baseline (964.663 us; speedup 1.0000x reference)
//
#include <hip/hip_runtime.h>
#include <hip/hip_bf16.h>

// Problem constants (from reference)
#define FEAT 64          // IN_F = HID_F = OUT_F
#define CAT_F 128        // HID_F + IN_F

// ---------------------------------------------------------------------------
// dtype detection: if edge_index was pushed as int64, the high 32-bit words of
// the first few (random, <100000) values are all zero. If int32, words 1,3,5,7
// are random edge endpoints (zero w.p. 1e-5 each).
__global__ void detect_kernel(const unsigned int* ei, int* mode) {
    *mode = (ei[1] == 0u && ei[3] == 0u && ei[5] == 0u && ei[7] == 0u) ? 1 : 0;
}

__global__ void convert_kernel(const void* __restrict__ in, int* __restrict__ out,
                               const int* __restrict__ mode, long n) {
    long i = blockIdx.x * (long)blockDim.x + threadIdx.x;
    if (i >= n) return;
    if (*mode)
        out[i] = (int)((const long long*)in)[i];
    else
        out[i] = ((const int*)in)[i];
}

// ---------------------------------------------------------------------------
// count out-degree (over row) and in-count (over col), skipping self loops
__global__ void count_kernel(const int* __restrict__ ei32, int* __restrict__ deg_cnt,
                             int* __restrict__ cnt_col, int E) {
    int e = blockIdx.x * blockDim.x + threadIdx.x;
    if (e >= E) return;
    int r = ei32[e];
    int c = ei32[E + e];
    if (r != c) {
        atomicAdd(&deg_cnt[r], 1);
        atomicAdd(&cnt_col[c], 1);
    }
}

__global__ void root_kernel(const int* __restrict__ batch32, int* __restrict__ root_idx,
                            int* __restrict__ gcount, int N) {
    int i = blockIdx.x * blockDim.x + threadIdx.x;
    if (i >= N) return;
    int b = batch32[i];
    atomicMin(&root_idx[b], i);
    atomicAdd(&gcount[b], 1);
}

__global__ void dis_kernel(const int* __restrict__ deg_cnt, float* __restrict__ dis, int N) {
    int i = blockIdx.x * blockDim.x + threadIdx.x;
    if (i >= N) return;
    dis[i] = rsqrtf(1.0f + (float)deg_cnt[i]);   // deg >= 1 (self loop)
}

// single-block exclusive scan of cnt_col -> offs[0..N], also copies to cursor
__global__ void scan_kernel(const int* __restrict__ cnt, int* __restrict__ offs,
                            int* __restrict__ cursor, int n) {
    __shared__ int partial[1024];
    int tid = threadIdx.x;
    int chunk = (n + 1023) / 1024;
    int start = tid * chunk;
    int end   = min(start + chunk, n);
    int s = 0;
    for (int i = start; i < end; ++i) s += cnt[i];
    partial[tid] = s;
    __syncthreads();
    for (int d = 1; d < 1024; d <<= 1) {
        int v = (tid >= d) ? partial[tid - d] : 0;
        __syncthreads();
        partial[tid] += v;
        __syncthreads();
    }
    int run = (tid == 0) ? 0 : partial[tid - 1];
    for (int i = start; i < end; ++i) {
        offs[i] = run;
        cursor[i] = run;
        run += cnt[i];
    }
    if (tid == 1023) offs[n] = run;
}

__global__ void scatter_kernel(const int* __restrict__ ei32, int* __restrict__ cursor,
                               int* __restrict__ erow, int E) {
    int e = blockIdx.x * blockDim.x + threadIdx.x;
    if (e >= E) return;
    int r = ei32[e];
    int c = ei32[E + e];
    if (r != c) {
        int slot = atomicAdd(&cursor[c], 1);
        erow[slot] = r;
    }
}

// ---------------------------------------------------------------------------
// h1 = x @ w1     x:[N,64] w:[64,64]  — one wave per row, lane = out feature
__global__ void gemm1_kernel(const float* __restrict__ x, const float* __restrict__ w,
                             float* __restrict__ out, int N) {
    __shared__ float ws[FEAT * FEAT];
    for (int i = threadIdx.x; i < FEAT * FEAT; i += blockDim.x) ws[i] = w[i];
    __syncthreads();
    int tid = blockIdx.x * blockDim.x + threadIdx.x;
    int row = tid >> 6;
    int f   = tid & 63;
    if (row >= N) return;
    const float* xr = x + (long)row * FEAT;
    float acc = 0.f;
#pragma unroll
    for (int k = 0; k < FEAT; ++k) acc += xr[k] * ws[k * FEAT + f];
    out[(long)row * FEAT + f] = acc;
}

// h2 = relu(concat(x2, x[root])) @ w2   w2:[128,64] — hcat fused on the fly
__global__ void gemm2_kernel(const float* __restrict__ x2, const float* __restrict__ x,
                             const int* __restrict__ root_idx, const int* __restrict__ batch32,
                             const float* __restrict__ w2, float* __restrict__ out, int N) {
    __shared__ float ws[CAT_F * FEAT];
    for (int i = threadIdx.x; i < CAT_F * FEAT; i += blockDim.x) ws[i] = w2[i];
    __syncthreads();
    int tid = blockIdx.x * blockDim.x + threadIdx.x;
    int row = tid >> 6;
    int f   = tid & 63;
    if (row >= N) return;
    int root = root_idx[batch32[row]];
    const float* a = x2 + (long)row * FEAT;
    const float* b = x  + (long)root * FEAT;
    float acc = 0.f;
#pragma unroll
    for (int k = 0; k < FEAT; ++k) acc += fmaxf(a[k], 0.f) * ws[k * FEAT + f];
#pragma unroll
    for (int k = 0; k < FEAT; ++k) acc += fmaxf(b[k], 0.f) * ws[(FEAT + k) * FEAT + f];
    out[(long)row * FEAT + f] = acc;
}

// aggregation: out[c] = dis[c] * sum_e dis[row_e]*h[row_e] + dis[c]^2*h[c] + bias
// one wave per node c, lane = feature
__global__ void agg_kernel(const float* __restrict__ h, const float* __restrict__ dis,
                           const int* __restrict__ offs, const int* __restrict__ erow,
                           const float* __restrict__ bias, float* __restrict__ out,
                           int N, int do_relu) {
    int wave = (blockIdx.x * blockDim.x + threadIdx.x) >> 6;
    int lane = threadIdx.x & 63;
    if (wave >= N) return;
    int c  = wave;
    int s0 = offs[c], s1 = offs[c + 1];
    float dc  = dis[c];
    float acc = 0.f;
    for (int base = s0; base < s1; base += 64) {
        int j = base + lane;
        int   r  = (j < s1) ? erow[j] : 0;
        float sr = (j < s1) ? dis[r] : 0.f;
        int kk = min(64, s1 - base);
        for (int t = 0; t < kk; ++t) {
            int   rr = __shfl(r, t, 64);
            float ss = __shfl(sr, t, 64);
            acc += ss * h[(long)rr * FEAT + lane];
        }
    }
    float v = dc * acc + dc * dc * h[(long)c * FEAT + lane] + bias[lane];
    if (do_relu) v = fmaxf(v, 0.f);
    out[(long)c * FEAT + lane] = v;
}

// per-graph mean (batch is sorted & contiguous): out[g][0:64] = mean relu(conv2),
// out[g][64:128] = x2[root_g]   (root_extend2 is constant within a graph)
__global__ void final_kernel(const float* __restrict__ conv2, const float* __restrict__ x2,
                             const int* __restrict__ root_idx, const int* __restrict__ gcount,
                             float* __restrict__ out) {
    int g = blockIdx.x;
    int f = threadIdx.x;            // 64 threads
    int root = root_idx[g];
    int cnt  = gcount[g];
    float s = 0.f;
    for (int n = 0; n < cnt; ++n) s += conv2[(long)(root + n) * FEAT + f];
    out[(long)g * CAT_F + f]        = s / (float)cnt;
    out[(long)g * CAT_F + FEAT + f] = x2[(long)root * FEAT + f];
}

// ---------------------------------------------------------------------------
extern "C" void kernel_launch(void* const* d_in, const int* in_sizes, int n_in,
                              void* d_out, int out_size, void* d_ws, size_t ws_size,
                              hipStream_t stream) {
    const float* x  = (const float*)d_in[0];
    const void*  ei = d_in[1];
    const void*  bt = d_in[2];
    const float* w1 = (const float*)d_in[3];
    const float* b1 = (const float*)d_in[4];
    const float* w2 = (const float*)d_in[5];
    const float* b2 = (const float*)d_in[6];
    float* out = (float*)d_out;

    const int N = in_sizes[0] / FEAT;     // 100000
    const int E = in_sizes[1] / 2;        // 1000000
    const int G = out_size / CAT_F;       // 500

    // workspace layout
    char* p = (char*)d_ws;
    size_t off = 0;
    auto alloc = [&](size_t bytes) {
        void* q = p + off;
        off = (off + bytes + 255) & ~(size_t)255;
        return q;
    };
    int*   mode     = (int*)  alloc(sizeof(int));
    int*   ei32     = (int*)  alloc((size_t)2 * E * sizeof(int));
    int*   batch32  = (int*)  alloc((size_t)N * sizeof(int));
    int*   deg_cnt  = (int*)  alloc((size_t)N * sizeof(int));
    float* dis      = (float*)alloc((size_t)N * sizeof(float));
    int*   cnt_col  = (int*)  alloc((size_t)N * sizeof(int));
    int*   offs     = (int*)  alloc((size_t)(N + 1) * sizeof(int));
    int*   cursor   = (int*)  alloc((size_t)N * sizeof(int));
    int*   erow     = (int*)  alloc((size_t)E * sizeof(int));
    int*   root_idx = (int*)  alloc((size_t)G * sizeof(int));
    int*   gcount   = (int*)  alloc((size_t)G * sizeof(int));
    float* h1       = (float*)alloc((size_t)N * FEAT * sizeof(float));  // reused as h2
    float* x2       = (float*)alloc((size_t)N * FEAT * sizeof(float));
    float* conv2    = (float*)alloc((size_t)N * FEAT * sizeof(float));
    (void)ws_size; (void)n_in;

    // zero/init per call (harness does not re-poison between replays)
    hipMemsetAsync(deg_cnt, 0,    (size_t)N * sizeof(int), stream);
    hipMemsetAsync(cnt_col, 0,    (size_t)N * sizeof(int), stream);
    hipMemsetAsync(root_idx, 0x7F,(size_t)G * sizeof(int), stream);
    hipMemsetAsync(gcount, 0,     (size_t)G * sizeof(int), stream);

    detect_kernel<<<1, 1, 0, stream>>>((const unsigned int*)ei, mode);
    {
        long n = (long)2 * E;
        convert_kernel<<<(unsigned)((n + 255) / 256), 256, 0, stream>>>(ei, ei32, mode, n);
        convert_kernel<<<(unsigned)((N + 255) / 256), 256, 0, stream>>>(bt, batch32, mode, (long)N);
    }

    count_kernel<<<(E + 255) / 256, 256, 0, stream>>>(ei32, deg_cnt, cnt_col, E);
    root_kernel <<<(N + 255) / 256, 256, 0, stream>>>(batch32, root_idx, gcount, N);
    dis_kernel  <<<(N + 255) / 256, 256, 0, stream>>>(deg_cnt, dis, N);
    scan_kernel <<<1, 1024, 0, stream>>>(cnt_col, offs, cursor, N);
    scatter_kernel<<<(E + 255) / 256, 256, 0, stream>>>(ei32, cursor, erow, E);

    const int gemm_blocks = (N * FEAT + 255) / 256;
    const int agg_blocks  = (N + 3) / 4;   // 4 waves per block

    gemm1_kernel<<<gemm_blocks, 256, 0, stream>>>(x, w1, h1, N);
    agg_kernel  <<<agg_blocks, 256, 0, stream>>>(h1, dis, offs, erow, b1, x2, N, 0);
    gemm2_kernel<<<gemm_blocks, 256, 0, stream>>>(x2, x, root_idx, batch32, w2, h1, N);
    agg_kernel  <<<agg_blocks, 256, 0, stream>>>(h1, dis, offs, erow, b2, conv2, N, 1);
    final_kernel<<<G, FEAT, 0, stream>>>(conv2, x2, root_idx, gcount, out);
}

// Round 2
// 751.051 us; speedup vs baseline: 1.2844x; 1.2844x over previous
//
#include <hip/hip_runtime.h>
#include <hip/hip_bf16.h>

// Problem constants (from reference)
#define FEAT 64          // IN_F = HID_F = OUT_F
#define CAT_F 128        // HID_F + IN_F

// ---------------------------------------------------------------------------
// dtype detection: if edge_index was pushed as int64, the high 32-bit words of
// the first few (random, <100000) values are all zero. If int32, words 1,3,5,7
// are random edge endpoints (zero w.p. 1e-5 each).
__global__ void detect_kernel(const unsigned int* ei, int* mode) {
    *mode = (ei[1] == 0u && ei[3] == 0u && ei[5] == 0u && ei[7] == 0u) ? 1 : 0;
}

__global__ void convert_kernel(const void* __restrict__ in, int* __restrict__ out,
                               const int* __restrict__ mode, long n) {
    long i = blockIdx.x * (long)blockDim.x + threadIdx.x;
    if (i >= n) return;
    if (*mode)
        out[i] = (int)((const long long*)in)[i];
    else
        out[i] = ((const int*)in)[i];
}

// ---------------------------------------------------------------------------
// count out-degree (over row) and in-count (over col), skipping self loops
__global__ void count_kernel(const int* __restrict__ ei32, int* __restrict__ deg_cnt,
                             int* __restrict__ cnt_col, int E) {
    int e = blockIdx.x * blockDim.x + threadIdx.x;
    if (e >= E) return;
    int r = ei32[e];
    int c = ei32[E + e];
    if (r != c) {
        atomicAdd(&deg_cnt[r], 1);
        atomicAdd(&cnt_col[c], 1);
    }
}

__global__ void root_kernel(const int* __restrict__ batch32, int* __restrict__ root_idx,
                            int* __restrict__ gcount, int N) {
    int i = blockIdx.x * blockDim.x + threadIdx.x;
    if (i >= N) return;
    int b = batch32[i];
    atomicMin(&root_idx[b], i);
    atomicAdd(&gcount[b], 1);
}

__global__ void dis_kernel(const int* __restrict__ deg_cnt, float* __restrict__ dis, int N) {
    int i = blockIdx.x * blockDim.x + threadIdx.x;
    if (i >= N) return;
    dis[i] = rsqrtf(1.0f + (float)deg_cnt[i]);   // deg >= 1 (self loop)
}

// ---------------------------------------------------------------------------
// device-wide exclusive scan: 1024 elements per block, 3 kernels
#define SCAN_TPB   256
#define SCAN_EPB   1024   // elements per block (SCAN_TPB * 4)

// k1: per-block sum of its 1024-element chunk
__global__ void scan_part1(const int* __restrict__ cnt, int* __restrict__ bsum, int n) {
    __shared__ int red[SCAN_TPB];
    int base = blockIdx.x * SCAN_EPB + threadIdx.x * 4;
    int s = 0;
#pragma unroll
    for (int k = 0; k < 4; ++k) {
        int i = base + k;
        if (i < n) s += cnt[i];
    }
    red[threadIdx.x] = s;
    __syncthreads();
    for (int d = SCAN_TPB / 2; d > 0; d >>= 1) {
        if (threadIdx.x < d) red[threadIdx.x] += red[threadIdx.x + d];
        __syncthreads();
    }
    if (threadIdx.x == 0) bsum[blockIdx.x] = red[0];
}

// k2: single block, exclusive scan of nb (<=1024) block sums; boffs[nb] = total
__global__ void scan_part2(const int* __restrict__ bsum, int* __restrict__ boffs, int nb) {
    __shared__ int sh[1024];
    int t = threadIdx.x;
    sh[t] = (t < nb) ? bsum[t] : 0;
    __syncthreads();
    for (int d = 1; d < 1024; d <<= 1) {
        int v = (t >= d) ? sh[t - d] : 0;
        __syncthreads();
        sh[t] += v;
        __syncthreads();
    }
    if (t <= nb) boffs[t] = (t == 0) ? 0 : sh[t - 1];
}

// k3: per-block local exclusive scan + block offset; writes offs & cursor
__global__ void scan_part3(const int* __restrict__ cnt, const int* __restrict__ boffs,
                           int* __restrict__ offs, int* __restrict__ cursor, int n, int nb) {
    __shared__ int tsum[SCAN_TPB];
    int base = blockIdx.x * SCAN_EPB + threadIdx.x * 4;
    int v[4];
    int s = 0;
#pragma unroll
    for (int k = 0; k < 4; ++k) {
        int i = base + k;
        v[k] = (i < n) ? cnt[i] : 0;
        s += v[k];
    }
    tsum[threadIdx.x] = s;
    __syncthreads();
    for (int d = 1; d < SCAN_TPB; d <<= 1) {
        int t = (threadIdx.x >= d) ? tsum[threadIdx.x - d] : 0;
        __syncthreads();
        tsum[threadIdx.x] += t;
        __syncthreads();
    }
    int run = boffs[blockIdx.x] + ((threadIdx.x == 0) ? 0 : tsum[threadIdx.x - 1]);
#pragma unroll
    for (int k = 0; k < 4; ++k) {
        int i = base + k;
        if (i < n) {
            offs[i] = run;
            cursor[i] = run;
            run += v[k];
        }
    }
    if (blockIdx.x == 0 && threadIdx.x == 0) offs[n] = boffs[nb];
}

__global__ void scatter_kernel(const int* __restrict__ ei32, int* __restrict__ cursor,
                               int* __restrict__ erow, int E) {
    int e = blockIdx.x * blockDim.x + threadIdx.x;
    if (e >= E) return;
    int r = ei32[e];
    int c = ei32[E + e];
    if (r != c) {
        int slot = atomicAdd(&cursor[c], 1);
        erow[slot] = r;
    }
}

// ---------------------------------------------------------------------------
// h1 = x @ w1     x:[N,64] w:[64,64]  — one wave per row, lane = out feature
__global__ void gemm1_kernel(const float* __restrict__ x, const float* __restrict__ w,
                             float* __restrict__ out, int N) {
    __shared__ float ws[FEAT * FEAT];
    for (int i = threadIdx.x; i < FEAT * FEAT; i += blockDim.x) ws[i] = w[i];
    __syncthreads();
    int tid = blockIdx.x * blockDim.x + threadIdx.x;
    int row = tid >> 6;
    int f   = tid & 63;
    if (row >= N) return;
    const float* xr = x + (long)row * FEAT;
    float acc = 0.f;
#pragma unroll
    for (int k = 0; k < FEAT; ++k) acc += xr[k] * ws[k * FEAT + f];
    out[(long)row * FEAT + f] = acc;
}

// h2 = relu(concat(x2, x[root])) @ w2   w2:[128,64] — hcat fused on the fly
__global__ void gemm2_kernel(const float* __restrict__ x2, const float* __restrict__ x,
                             const int* __restrict__ root_idx, const int* __restrict__ batch32,
                             const float* __restrict__ w2, float* __restrict__ out, int N) {
    __shared__ float ws[CAT_F * FEAT];
    for (int i = threadIdx.x; i < CAT_F * FEAT; i += blockDim.x) ws[i] = w2[i];
    __syncthreads();
    int tid = blockIdx.x * blockDim.x + threadIdx.x;
    int row = tid >> 6;
    int f   = tid & 63;
    if (row >= N) return;
    int root = root_idx[batch32[row]];
    const float* a = x2 + (long)row * FEAT;
    const float* b = x  + (long)root * FEAT;
    float acc = 0.f;
#pragma unroll
    for (int k = 0; k < FEAT; ++k) acc += fmaxf(a[k], 0.f) * ws[k * FEAT + f];
#pragma unroll
    for (int k = 0; k < FEAT; ++k) acc += fmaxf(b[k], 0.f) * ws[(FEAT + k) * FEAT + f];
    out[(long)row * FEAT + f] = acc;
}

// aggregation: out[c] = dis[c] * sum_e dis[row_e]*h[row_e] + dis[c]^2*h[c] + bias
// one wave per node c, lane = feature
__global__ void agg_kernel(const float* __restrict__ h, const float* __restrict__ dis,
                           const int* __restrict__ offs, const int* __restrict__ erow,
                           const float* __restrict__ bias, float* __restrict__ out,
                           int N, int do_relu) {
    int wave = (blockIdx.x * blockDim.x + threadIdx.x) >> 6;
    int lane = threadIdx.x & 63;
    if (wave >= N) return;
    int c  = wave;
    int s0 = offs[c], s1 = offs[c + 1];
    float dc  = dis[c];
    float acc = 0.f;
    for (int base = s0; base < s1; base += 64) {
        int j = base + lane;
        int   r  = (j < s1) ? erow[j] : 0;
        float sr = (j < s1) ? dis[r] : 0.f;
        int kk = min(64, s1 - base);
        for (int t = 0; t < kk; ++t) {
            int   rr = __shfl(r, t, 64);
            float ss = __shfl(sr, t, 64);
            acc += ss * h[(long)rr * FEAT + lane];
        }
    }
    float v = dc * acc + dc * dc * h[(long)c * FEAT + lane] + bias[lane];
    if (do_relu) v = fmaxf(v, 0.f);
    out[(long)c * FEAT + lane] = v;
}

// per-graph mean (batch is sorted & contiguous): out[g][0:64] = mean relu(conv2),
// out[g][64:128] = x2[root_g]   (root_extend2 is constant within a graph)
__global__ void final_kernel(const float* __restrict__ conv2, const float* __restrict__ x2,
                             const int* __restrict__ root_idx, const int* __restrict__ gcount,
                             float* __restrict__ out) {
    int g = blockIdx.x;
    int f = threadIdx.x;            // 64 threads
    int root = root_idx[g];
    int cnt  = gcount[g];
    float s = 0.f;
    for (int n = 0; n < cnt; ++n) s += conv2[(long)(root + n) * FEAT + f];
    out[(long)g * CAT_F + f]        = s / (float)cnt;
    out[(long)g * CAT_F + FEAT + f] = x2[(long)root * FEAT + f];
}

// ---------------------------------------------------------------------------
extern "C" void kernel_launch(void* const* d_in, const int* in_sizes, int n_in,
                              void* d_out, int out_size, void* d_ws, size_t ws_size,
                              hipStream_t stream) {
    const float* x  = (const float*)d_in[0];
    const void*  ei = d_in[1];
    const void*  bt = d_in[2];
    const float* w1 = (const float*)d_in[3];
    const float* b1 = (const float*)d_in[4];
    const float* w2 = (const float*)d_in[5];
    const float* b2 = (const float*)d_in[6];
    float* out = (float*)d_out;

    const int N = in_sizes[0] / FEAT;     // 100000
    const int E = in_sizes[1] / 2;        // 1000000
    const int G = out_size / CAT_F;       // 500

    // workspace layout
    char* p = (char*)d_ws;
    size_t off = 0;
    auto alloc = [&](size_t bytes) {
        void* q = p + off;
        off = (off + bytes + 255) & ~(size_t)255;
        return q;
    };
    int*   mode     = (int*)  alloc(sizeof(int));
    int*   ei32     = (int*)  alloc((size_t)2 * E * sizeof(int));
    int*   batch32  = (int*)  alloc((size_t)N * sizeof(int));
    int*   deg_cnt  = (int*)  alloc((size_t)N * sizeof(int));
    float* dis      = (float*)alloc((size_t)N * sizeof(float));
    int*   cnt_col  = (int*)  alloc((size_t)N * sizeof(int));
    int*   offs     = (int*)  alloc((size_t)(N + 1) * sizeof(int));
    int*   cursor   = (int*)  alloc((size_t)N * sizeof(int));
    int*   erow     = (int*)  alloc((size_t)E * sizeof(int));
    int*   root_idx = (int*)  alloc((size_t)G * sizeof(int));
    int*   gcount   = (int*)  alloc((size_t)G * sizeof(int));
    int*   bsum     = (int*)  alloc((size_t)1024 * sizeof(int));
    int*   boffs    = (int*)  alloc((size_t)1025 * sizeof(int));
    float* h1       = (float*)alloc((size_t)N * FEAT * sizeof(float));  // reused as h2
    float* x2       = (float*)alloc((size_t)N * FEAT * sizeof(float));
    float* conv2    = (float*)alloc((size_t)N * FEAT * sizeof(float));
    (void)ws_size; (void)n_in;

    // zero/init per call (harness does not re-poison between replays)
    hipMemsetAsync(deg_cnt, 0,    (size_t)N * sizeof(int), stream);
    hipMemsetAsync(cnt_col, 0,    (size_t)N * sizeof(int), stream);
    hipMemsetAsync(root_idx, 0x7F,(size_t)G * sizeof(int), stream);
    hipMemsetAsync(gcount, 0,     (size_t)G * sizeof(int), stream);

    detect_kernel<<<1, 1, 0, stream>>>((const unsigned int*)ei, mode);
    {
        long n = (long)2 * E;
        convert_kernel<<<(unsigned)((n + 255) / 256), 256, 0, stream>>>(ei, ei32, mode, n);
        convert_kernel<<<(unsigned)((N + 255) / 256), 256, 0, stream>>>(bt, batch32, mode, (long)N);
    }

    count_kernel<<<(E + 255) / 256, 256, 0, stream>>>(ei32, deg_cnt, cnt_col, E);
    root_kernel <<<(N + 255) / 256, 256, 0, stream>>>(batch32, root_idx, gcount, N);
    dis_kernel  <<<(N + 255) / 256, 256, 0, stream>>>(deg_cnt, dis, N);

    // device-wide exclusive scan of cnt_col -> offs / cursor
    const int nb = (N + SCAN_EPB - 1) / SCAN_EPB;   // 98 for N=100000 (<=1024)
    scan_part1<<<nb, SCAN_TPB, 0, stream>>>(cnt_col, bsum, N);
    scan_part2<<<1, 1024, 0, stream>>>(bsum, boffs, nb);
    scan_part3<<<nb, SCAN_TPB, 0, stream>>>(cnt_col, boffs, offs, cursor, N, nb);

    scatter_kernel<<<(E + 255) / 256, 256, 0, stream>>>(ei32, cursor, erow, E);

    const int gemm_blocks = (N * FEAT + 255) / 256;
    const int agg_blocks  = (N + 3) / 4;   // 4 waves per block

    gemm1_kernel<<<gemm_blocks, 256, 0, stream>>>(x, w1, h1, N);
    agg_kernel  <<<agg_blocks, 256, 0, stream>>>(h1, dis, offs, erow, b1, x2, N, 0);
    gemm2_kernel<<<gemm_blocks, 256, 0, stream>>>(x2, x, root_idx, batch32, w2, h1, N);
    agg_kernel  <<<agg_blocks, 256, 0, stream>>>(h1, dis, offs, erow, b2, conv2, N, 1);
    final_kernel<<<G, FEAT, 0, stream>>>(conv2, x2, root_idx, gcount, out);
}